// Round 1
// baseline (143.730 us; speedup 1.0000x reference)
//
#include <hip/hip_runtime.h>

typedef __attribute__((ext_vector_type(8))) short bf16x8;
typedef __attribute__((ext_vector_type(4))) float f32x4;
typedef __attribute__((ext_vector_type(4))) int i32x4;
typedef __attribute__((ext_vector_type(4))) unsigned short u16x4;

#define KDIM 256
#define HWSZ 4096
#define NOUT 765
#define NOUTP 768

// Anchors in PIXEL units (ANCHORS). Note w_a = ANCHORS/16 (grid units), and every
// use multiplies by STRIDE=16 again, so pixel-unit anchors are what we need.
// Index 9 is a dummy for the padded o in [765,768) (never stored).
__constant__ float c_AW[10] = {10.f,16.f,33.f,30.f,62.f,59.f,116.f,156.f,373.f,0.f};
__constant__ float c_AH[10] = {13.f,30.f,23.f,61.f,45.f,119.f,90.f,198.f,326.f,0.f};

__device__ __forceinline__ unsigned short f2bf(float f) {
  unsigned u = __builtin_bit_cast(unsigned, f);
  u += 0x7fffu + ((u >> 16) & 1u);   // RNE
  return (unsigned short)(u >> 16);
}

__device__ __forceinline__ float sigf(float t) {
  return 1.0f / (1.0f + __expf(-t));
}

// ---- kernel 1: conv_w (765x256 f32) -> padded bf16 (768x256), rows 765..767 = 0
__global__ void prep_w(const float* __restrict__ cw, unsigned short* __restrict__ wbf) {
  int e = (blockIdx.x * 256 + threadIdx.x) * 4;   // element quad
  int o = e >> 8, col = e & 255;
  f32x4 v = {0.f, 0.f, 0.f, 0.f};
  if (o < NOUT) v = *reinterpret_cast<const f32x4*>(cw + o * KDIM + col);
  u16x4 u = { f2bf(v.x), f2bf(v.y), f2bf(v.z), f2bf(v.w) };
  *reinterpret_cast<u16x4*>(wbf + e) = u;
}

// ---- kernel 2: per block = one batch x one 64-pixel image row, all 765 outputs.
// 8 waves: wave wv owns output channels [96*wv, 96*wv+96) x all 64 pixels.
// GEMM: D[px][o] = sum_k X^T[px][k] * W[o][k] via mfma_f32_16x16x32_bf16 with
// A = X-tile (row=px), B = W-tile (col=o). Both fragments loaded with the same
// assumed (group,reg)->k mapping, so any hardware k-permutation cancels.
__global__ __launch_bounds__(512, 2) void yolo_main(
    const float* __restrict__ xin,
    const unsigned short* __restrict__ wbf,
    const float* __restrict__ bias,
    float* __restrict__ out)
{
  __shared__ __align__(16) unsigned short xT[64 * KDIM];  // [px][k] bf16, k-bits 3..5 XOR-swizzled by (px&7)

  const int b    = blockIdx.x >> 6;
  const int pc   = blockIdx.x & 63;    // image row (y)
  const int tid  = threadIdx.x;
  const int lane = tid & 63;
  const int wv   = tid >> 6;

  // ---------- stage X^T into LDS (f32 -> bf16, swizzled) ----------
  {
    const float* xsrc = xin + ((size_t)b * KDIM) * HWSZ + pc * 64;
    const int p  = lane;               // pixel 0..63 (coalesced 256B per c-row)
    const int sw = (p & 7) << 3;
    #pragma unroll
    for (int i = 0; i < 4; ++i) {
      const int c0 = (wv + 8 * i) << 3;     // c-octant; 8 waves x 4 iters cover c=0..255
      float v[8];
      #pragma unroll
      for (int j = 0; j < 8; ++j) v[j] = xsrc[(size_t)(c0 + j) * HWSZ + p];
      union { i32x4 q; unsigned short us[8]; } pk;
      #pragma unroll
      for (int j = 0; j < 8; ++j) pk.us[j] = f2bf(v[j]);
      *reinterpret_cast<i32x4*>(&xT[(p << 8) + (c0 ^ sw)]) = pk.q;   // b128, bank-even
    }
  }
  __syncthreads();

  const int g     = lane >> 4;
  const int r16   = lane & 15;
  const int obase = wv * 96;

  f32x4 acc[6][4];
  #pragma unroll
  for (int ot = 0; ot < 6; ++ot)
    #pragma unroll
    for (int pt = 0; pt < 4; ++pt)
      acc[ot][pt] = f32x4{0.f, 0.f, 0.f, 0.f};

  // W fragment base: row (obase+r16), k offset 8*g. Reads are 64B-contiguous per row.
  const unsigned short* wptr = wbf + (size_t)(obase + r16) * KDIM + 8 * g;

  #pragma unroll
  for (int kk = 0; kk < 8; ++kk) {
    bf16x8 xfr[4];
    #pragma unroll
    for (int pt = 0; pt < 4; ++pt) {
      const int pxl = pt * 16 + r16;
      const int e   = (pxl << 8) + ((kk * 32 + 8 * g) ^ ((pxl & 7) << 3));
      xfr[pt] = __builtin_bit_cast(bf16x8, *reinterpret_cast<const i32x4*>(&xT[e]));
    }
    #pragma unroll
    for (int ot = 0; ot < 6; ++ot) {
      bf16x8 wfr = __builtin_bit_cast(bf16x8,
          *reinterpret_cast<const i32x4*>(wptr + ot * 16 * KDIM + kk * 32));
      #pragma unroll
      for (int pt = 0; pt < 4; ++pt)
        acc[ot][pt] = __builtin_amdgcn_mfma_f32_16x16x32_bf16(xfr[pt], wfr, acc[ot][pt], 0, 0, 0);
    }
  }

  // ---------- decode + store ----------
  // D layout: col = r16 -> o = obase + ot*16 + r16 ; row = 4*g + r -> px = pt*16 + 4g + r.
  // Lanes 0..15 write 16 consecutive channel floats -> full 64B lines.
  const float ys = (float)pc * 16.0f;
  #pragma unroll
  for (int ot = 0; ot < 6; ++ot) {
    const int o = obase + ot * 16 + r16;
    int a = o / 85;
    const int ch = o - a * 85;
    if (a > 8) a = 8;                       // clamp padded region (never stored)
    const bool valid = (o < NOUT);
    const float aw = c_AW[a], ah = c_AH[a];
    const float bi = valid ? bias[o] : 0.0f;
    #pragma unroll
    for (int pt = 0; pt < 4; ++pt) {
      #pragma unroll
      for (int r = 0; r < 4; ++r) {
        const int   pxl = pt * 16 + g * 4 + r;
        const float t   = acc[ot][pt][r] + bi;
        float val;
        if (ch >= 4)      val = sigf(t);
        else if (ch == 0) val = (sigf(t) - 0.5f) * aw + (float)pxl * 16.0f;
        else if (ch == 1) val = (sigf(t) - 0.5f) * ah + ys;
        else if (ch == 2) val = __expf(t) * aw;
        else              val = __expf(t) * ah;
        if (valid) {
          const size_t addr = (((size_t)(b * 9 + a) * HWSZ) + (size_t)(pc * 64 + pxl)) * 85 + ch;
          out[addr] = val;
        }
      }
    }
  }
}

extern "C" void kernel_launch(void* const* d_in, const int* in_sizes, int n_in,
                              void* d_out, int out_size, void* d_ws, size_t ws_size,
                              hipStream_t stream) {
  const float* xin = (const float*)d_in[0];
  const float* cw  = (const float*)d_in[1];
  const float* cb  = (const float*)d_in[2];
  float* out = (float*)d_out;
  unsigned short* wbf = (unsigned short*)d_ws;   // 768*256*2 = 393216 bytes

  prep_w<<<dim3((NOUTP * KDIM / 4) / 256), dim3(256), 0, stream>>>(cw, wbf);
  yolo_main<<<dim3(16 * 64), dim3(512), 0, stream>>>(xin, wbf, cb, out);
}